// Round 5
// baseline (312.066 us; speedup 1.0000x reference)
//
#include <hip/hip_runtime.h>

// VQGAN VectorQuantizer forward — MFMA bf16-split edition.
// z: (32,256,32,32) f32, emb: (1024,256) f32.
// d_out (float): [0..8388607] z_q | [8388608] loss | [8388609..] indices.
//
// Score GEMM runs as 3 bf16 MFMA GEMMs (z1e1+z1e2+z2e1, 2-term RNE splits) into
// one f32 accumulator. Rows whose top-2 margin > 1.5e-4 provably match the np-f32
// quantized reference argmin (margin > 2*(ulp(512)+2*delta_dot) + binade slack).
// Rows under the gate are re-solved by k_refine with the EXACT round-3/4
// arithmetic (serial fmaf dot, same A/B stashes) which passed fully twice.
//
// Scratch in the z_q region of d_out (dead until k_gather overwrites it):
//   F[0..1023]            B_k = ||emb_k||^2
//   int F[1536]           refine count        F[98304..131071]  refine row list
//   F[2048..34815]        A_n = ||z_n||^2
//   F[131072..655359]     pv1[16][32768]   per-(ct,wc)-chunk best
//   F[655360..1179647]    pi1[16][32768]   per-chunk best index
//   F[1179648..1703935]   pv2[16][32768]   per-chunk 2nd-best

#define DDIM 256
#define LOSS_OFF 8388608
#define IDX_OFF 8388609
#define B_BASE 0
#define CNT_SLOT 1536
#define A_BASE 2048
#define LIST_BASE 98304
#define PV1_BASE 131072
#define PI1_BASE 655360
#define PV2_BASE 1179648
#define REFINE_THR 1.5e-4f

typedef __attribute__((ext_vector_type(8))) short bf16x8;
typedef __attribute__((ext_vector_type(4))) float f32x4;
typedef __attribute__((ext_vector_type(8))) ushort u16x8;

__device__ __forceinline__ ushort bf16_rne(float x) {
  unsigned u = __float_as_uint(x);
  return (ushort)((u + 0x7FFFu + ((u >> 16) & 1u)) >> 16);
}
__device__ __forceinline__ float bf16f(ushort h) {
  return __uint_as_float(((unsigned)h) << 16);
}

// ---------------- A1: B_k = ||emb_k||^2 ; zero loss & refine count ----------
__global__ __launch_bounds__(256) void k_enorm(const float* __restrict__ emb,
                                               float* __restrict__ out) {
  const int tid = threadIdx.x;
  if (blockIdx.x == 0 && tid == 0) {
    out[LOSS_OFF] = 0.0f;
    ((int*)out)[CNT_SLOT] = 0;
  }
  const int lane = tid & 63;
  const int row = blockIdx.x * 4 + (tid >> 6);
  const float4 v = *(const float4*)(emb + row * DDIM + lane * 4);
  float s = v.x * v.x + v.y * v.y + v.z * v.z + v.w * v.w;
#pragma unroll
  for (int off = 32; off; off >>= 1) s += __shfl_down(s, off);
  if (lane == 0) out[row] = s;
}

// ---------------- A2: A_n = ||z_n||^2 (bit-identical to rounds 3/4) ---------
__global__ __launch_bounds__(256) void k_znorm(const float* __restrict__ z,
                                               float* __restrict__ out) {
  const int n = blockIdx.x * 256 + threadIdx.x;
  const int b = n >> 10, hw = n & 1023;
  const float* p = z + b * 262144 + hw;
  float a[8] = {0.f, 0.f, 0.f, 0.f, 0.f, 0.f, 0.f, 0.f};
  for (int d = 0; d < 256; d += 8) {
#pragma unroll
    for (int j = 0; j < 8; ++j) {
      const float v = p[(d + j) * 1024];
      a[j] = fmaf(v, v, a[j]);
    }
  }
  out[A_BASE + n] = ((a[0] + a[1]) + (a[2] + a[3])) + ((a[4] + a[5]) + (a[6] + a[7]));
}

// ---------------- B: MFMA score GEMM + per-chunk top-2 ----------------------
// BM=256 x BN=128, BK=32, 512 threads (8 waves, 2Mx... wave grid 4r x 2c,
// 64x64 per wave). LDS: z1,z2 [256][32] + e1,e2 [128][32] bf16, double-buffered
// (96 KB), XOR slot swizzle (kq ^ ((m>>2)&3)). Grid 1024 = 128 rt x 8 ct with
// XCD remap so the 8 ct-tiles sharing one Z-tile land on one XCD's L2.
__global__ __launch_bounds__(512, 2) void k_score(const float* __restrict__ z,
                                                  const float* __restrict__ emb,
                                                  float* __restrict__ out) {
  __shared__ __align__(16) ushort lds[2][24576];
  const int tid = threadIdx.x;
  const int id = blockIdx.x;
  const int xcd = id & 7, qq = id >> 3;
  const int ct = qq & 7;
  const int rt = ((qq >> 3) << 3) + xcd;   // 0..127
  const int row0 = rt << 8;                // 256 rows, same b (256 | 1024)
  const int k0e = ct << 7;                 // 128 codes
  const float* zb = z + (row0 >> 10) * 262144 + (row0 & 1023);

  // staging roles
  const int sm = tid & 255;                // Z row in tile
  const int kh = tid >> 8;                 // which 16-k half
  const int szsw = (sm >> 2) & 3;
  const int en = tid & 127;                // E col in tile
  const int dq = tid >> 7;                 // 0..3 (8-d slot)
  const int esw = (en >> 2) & 3;
  const float* ep = emb + (k0e + en) * DDIM;

  float zv[16], ev[8];
  auto sload = [&](int s) {
    const int d0 = (s << 5) + (kh << 4);
#pragma unroll
    for (int kk = 0; kk < 16; ++kk) zv[kk] = zb[((d0 + kk) << 10) + sm];
    const float4 e0 = *(const float4*)(ep + (s << 5) + (dq << 3));
    const float4 e1 = *(const float4*)(ep + (s << 5) + (dq << 3) + 4);
    ev[0] = e0.x; ev[1] = e0.y; ev[2] = e0.z; ev[3] = e0.w;
    ev[4] = e1.x; ev[5] = e1.y; ev[6] = e1.z; ev[7] = e1.w;
  };
  auto swrite = [&](int bf) {
    ushort h[16], l[16];
#pragma unroll
    for (int kk = 0; kk < 16; ++kk) {
      h[kk] = bf16_rne(zv[kk]);
      l[kk] = bf16_rne(zv[kk] - bf16f(h[kk]));   // exact residual (Sterbenz)
    }
#pragma unroll
    for (int j = 0; j < 2; ++j) {
      const int slot = ((kh << 1) + j) ^ szsw;
      u16x8 ph, pl;
#pragma unroll
      for (int r = 0; r < 8; ++r) { ph[r] = h[j * 8 + r]; pl[r] = l[j * 8 + r]; }
      *(u16x8*)&lds[bf][sm * 32 + slot * 8] = ph;
      *(u16x8*)&lds[bf][8192 + sm * 32 + slot * 8] = pl;
    }
    ushort eh[8], el[8];
#pragma unroll
    for (int r = 0; r < 8; ++r) {
      eh[r] = bf16_rne(ev[r]);
      el[r] = bf16_rne(ev[r] - bf16f(eh[r]));
    }
    const int eslot = dq ^ esw;
    u16x8 phh, pll;
#pragma unroll
    for (int r = 0; r < 8; ++r) { phh[r] = eh[r]; pll[r] = el[r]; }
    *(u16x8*)&lds[bf][16384 + en * 32 + eslot * 8] = phh;
    *(u16x8*)&lds[bf][20480 + en * 32 + eslot * 8] = pll;
  };

  const int L = tid & 63, w = tid >> 6;
  const int wr = w >> 1, wc = w & 1;       // 4 x 2 wave grid
  const int l15 = L & 15, kq = L >> 4;

  f32x4 acc[4][4];
#pragma unroll
  for (int i = 0; i < 4; ++i)
#pragma unroll
    for (int j = 0; j < 4; ++j) acc[i][j] = (f32x4){0.f, 0.f, 0.f, 0.f};

  sload(0);
  swrite(0);
  __syncthreads();

  for (int s = 0; s < 8; ++s) {
    const int cur = s & 1;
    if (s < 7) sload(s + 1);
    bf16x8 a1[4], a2[4], b1[4], b2[4];
#pragma unroll
    for (int mi = 0; mi < 4; ++mi) {
      const int m = (wr << 6) + (mi << 4) + l15;
      const int off = m * 32 + ((kq ^ ((m >> 2) & 3)) << 3);
      a1[mi] = *(const bf16x8*)&lds[cur][off];
      a2[mi] = *(const bf16x8*)&lds[cur][8192 + off];
    }
#pragma unroll
    for (int nj = 0; nj < 4; ++nj) {
      const int n = (wc << 6) + (nj << 4) + l15;
      const int off = n * 32 + ((kq ^ ((n >> 2) & 3)) << 3);
      b1[nj] = *(const bf16x8*)&lds[cur][16384 + off];
      b2[nj] = *(const bf16x8*)&lds[cur][20480 + off];
    }
    __syncthreads();                 // all reads of buf `cur` done
    if (s < 7) swrite(cur ^ 1);      // fill next buf (overlaps MFMA of others)
#pragma unroll
    for (int mi = 0; mi < 4; ++mi)
#pragma unroll
      for (int nj = 0; nj < 4; ++nj) {
        acc[mi][nj] = __builtin_amdgcn_mfma_f32_16x16x32_bf16(a2[mi], b1[nj], acc[mi][nj], 0, 0, 0);
        acc[mi][nj] = __builtin_amdgcn_mfma_f32_16x16x32_bf16(a1[mi], b2[nj], acc[mi][nj], 0, 0, 0);
        acc[mi][nj] = __builtin_amdgcn_mfma_f32_16x16x32_bf16(a1[mi], b1[nj], acc[mi][nj], 0, 0, 0);
      }
    __syncthreads();                 // writes complete before next reads
  }

  // epilogue: quantized score + per-chunk (v1, i1, v2)
  const int tc = (ct << 1) + wc;
#pragma unroll
  for (int mi = 0; mi < 4; ++mi) {
#pragma unroll
    for (int r = 0; r < 4; ++r) {
      const int rowl = (wr << 6) + (mi << 4) + (kq << 2) + r;  // C row
      const int ng = row0 + rowl;
      const float A = out[A_BASE + ng];
      float v1 = 3.0e38f, v2 = 3.0e38f;
      int i1 = 0;
#pragma unroll
      for (int nj = 0; nj < 4; ++nj) {
        const int kg = k0e + (wc << 6) + (nj << 4) + l15;       // C col
        const float B = out[B_BASE + kg];
        const float sc = fmaf(-2.0f, acc[mi][nj][r], A + B);    // np-f32 formula
        if (sc < v1) { v2 = v1; v1 = sc; i1 = kg; }             // nj ascending k
        else if (sc < v2) v2 = sc;
      }
#pragma unroll
      for (int o = 1; o < 16; o <<= 1) {
        const float ov1 = __shfl_xor(v1, o);
        const float ov2 = __shfl_xor(v2, o);
        const int oi1 = __shfl_xor(i1, o);
        v2 = fminf(fminf(v2, ov2), fmaxf(v1, ov1));
        if (ov1 < v1 || (ov1 == v1 && oi1 < i1)) { v1 = ov1; i1 = oi1; }
      }
      if (l15 == 0) {
        const int base = (tc << 15) + ng;
        out[PV1_BASE + base] = v1;
        out[PI1_BASE + base] = (float)i1;
        out[PV2_BASE + base] = v2;
      }
    }
  }
}

// ---------------- B2: merge 16 chunks; margin gate -> refine list -----------
__global__ __launch_bounds__(256) void k_reduce(float* __restrict__ out) {
  const int row = blockIdx.x * 256 + threadIdx.x;
  float v1 = 3.0e38f, v2 = 3.0e38f, i1 = 0.f;
#pragma unroll
  for (int tc = 0; tc < 16; ++tc) {   // ascending k-ranges: first-index ties
    const int base = (tc << 15) + row;
    const float a1 = out[PV1_BASE + base];
    const float ai = out[PI1_BASE + base];
    const float a2 = out[PV2_BASE + base];
    if (a1 < v1) { v2 = fminf(v1, a2); v1 = a1; i1 = ai; }
    else v2 = fminf(v2, a1);
  }
  out[IDX_OFF + row] = i1;
  if (v2 - v1 < REFINE_THR) {
    const int slot = atomicAdd((int*)out + CNT_SLOT, 1);
    ((int*)out)[LIST_BASE + slot] = row;
  }
}

// ---------------- B3: exact round-3 re-solve for gated rows -----------------
__global__ __launch_bounds__(256) void k_refine(const float* __restrict__ z,
                                                const float* __restrict__ emb,
                                                float* __restrict__ out) {
  __shared__ float zs[DDIM];
  __shared__ float sv[256];
  __shared__ int si[256];
  const int t = threadIdx.x;
  const int cnt = ((const int*)out)[CNT_SLOT];
  for (int e = blockIdx.x; e < cnt; e += gridDim.x) {
    const int row = ((const int*)out)[LIST_BASE + e];
    const int b = row >> 10, hw = row & 1023;
    zs[t] = z[b * 262144 + (t << 10) + hw];
    __syncthreads();
    const float A = out[A_BASE + row];
    float bv = 3.0e38f;
    int bi = 0;
#pragma unroll
    for (int q = 0; q < 4; ++q) {
      const int k = (q << 8) + t;               // ascending within thread
      const float* er = emb + k * DDIM;
      float s = 0.f;
      for (int d = 0; d < DDIM; ++d) s = fmaf(zs[d], er[d], s);  // round-3 chain
      const float sc = fmaf(-2.0f, s, A + out[B_BASE + k]);
      if (sc < bv) { bv = sc; bi = k; }
    }
    sv[t] = bv; si[t] = bi;
    __syncthreads();
    for (int o = 128; o; o >>= 1) {
      if (t < o) {
        if (sv[t + o] < sv[t] || (sv[t + o] == sv[t] && si[t + o] < si[t])) {
          sv[t] = sv[t + o]; si[t] = si[t + o];
        }
      }
      __syncthreads();
    }
    if (t == 0) out[IDX_OFF + row] = (float)si[0];
    __syncthreads();
  }
}

// ---------------- C: z_q gather + loss ----------------
__global__ __launch_bounds__(256) void k_gather(const float* __restrict__ z,
                                                const float* __restrict__ emb,
                                                float* __restrict__ out) {
  const int tid = threadIdx.x;
  const int e0 = (blockIdx.x * 256 + tid) * 16;
  const int b = e0 >> 18;
  const int c = (e0 >> 10) & 255;
  const int n0 = (b << 10) + (e0 & 1023);
  float acc = 0.f;
#pragma unroll
  for (int g = 0; g < 4; ++g) {
    const float4 zv = *(const float4*)(z + e0 + g * 4);
    const float zz[4] = {zv.x, zv.y, zv.z, zv.w};
    float q[4];
#pragma unroll
    for (int j = 0; j < 4; ++j) {
      const int id = (int)(out[IDX_OFF + n0 + g * 4 + j] + 0.5f);
      const float e = emb[id * DDIM + c];
      q[j] = e;
      const float d = e - zz[j];
      acc = fmaf(d, d, acc);
    }
    const float4 qv = {q[0], q[1], q[2], q[3]};
    *(float4*)(out + e0 + g * 4) = qv;
  }
#pragma unroll
  for (int off = 32; off; off >>= 1) acc += __shfl_down(acc, off);
  __shared__ float sm[4];
  if ((tid & 63) == 0) sm[tid >> 6] = acc;
  __syncthreads();
  if (tid == 0)
    atomicAdd(out + LOSS_OFF,
              (sm[0] + sm[1] + sm[2] + sm[3]) * (1.25f / 8388608.0f));
}

extern "C" void kernel_launch(void* const* d_in, const int* in_sizes, int n_in,
                              void* d_out, int out_size, void* d_ws, size_t ws_size,
                              hipStream_t stream) {
  const float* z = (const float*)d_in[0];
  const float* emb = (const float*)d_in[1];
  float* out = (float*)d_out;

  k_enorm<<<256, 256, 0, stream>>>(emb, out);
  k_znorm<<<128, 256, 0, stream>>>(z, out);
  k_score<<<1024, 512, 0, stream>>>(z, emb, out);
  k_reduce<<<128, 256, 0, stream>>>(out);
  k_refine<<<256, 256, 0, stream>>>(z, emb, out);
  k_gather<<<2048, 256, 0, stream>>>(z, emb, out);
}

// Round 6
// 212.351 us; speedup vs baseline: 1.4696x; 1.4696x over previous
//
#include <hip/hip_runtime.h>

// VQGAN VectorQuantizer forward — MFMA bf16-presplit edition.
// z: (32,256,32,32) f32, emb: (1024,256) f32.
// d_out (float): [0..8388607] z_q | [8388608] loss | [8388609..] indices.
//
// Numerics: scores replicate np-f32 quantized formula s = fl(fl(A+B) - 2*dot).
// Main pass: dot via 3 bf16 MFMA GEMMs (z1e1+z1e2+z2e1; 2-term RNE splits).
// Per-code |s_np - s_mine| <= 8e-6 + one grid step (6.1e-5) => rows with top-2
// margin > 1.5e-4 provably match np's argmin. Gated rows re-solved by k_refine
// with the EXACT round-3 serial-fmaf chain, scanning only chunks whose best is
// within THR of the global best (provable superset of np-preferable codes).
//
// z_q region of d_out (dead until k_gather) holds z1t,z2t bf16 tiles (32 MB,
// exactly 8388608 float slots). All other scratch lives in d_ws (~7.3 MB):
#define WS_B 0            // [1024]   B_k = ||emb_k||^2
#define WS_A 1024         // [32768]  A_n = ||z_n||^2
#define WS_PV1 33792      // [16][32768] per-chunk best score
#define WS_PI1 558080     // [16][32768] per-chunk best index
#define WS_PV2 1082368    // [16][32768] per-chunk 2nd-best
#define WS_E1 1606656     // 262144 ushorts (e1 tiles)
#define WS_E2 1737728     // 262144 ushorts (e2 tiles)
#define WS_LIST 1868800   // [32768] int refine rows
#define WS_CNT 1901568    // int refine count
// total 1901569 floats ~= 7.3 MB required in d_ws.

#define DDIM 256
#define LOSS_OFF 8388608
#define IDX_OFF 8388609
#define Z2T_OFF 8388608   // ushort offset of z2t within out
#define REFINE_THR 1.5e-4f

typedef __attribute__((ext_vector_type(8))) short bf16x8;
typedef __attribute__((ext_vector_type(4))) float f32x4;
typedef __attribute__((ext_vector_type(8))) ushort u16x8;

__device__ __forceinline__ ushort bf16_rne(float x) {
  unsigned u = __float_as_uint(x);
  return (ushort)((u + 0x7FFFu + ((u >> 16) & 1u)) >> 16);
}
__device__ __forceinline__ float bf16f(ushort h) {
  return __uint_as_float(((unsigned)h) << 16);
}
__device__ __forceinline__ void gld16(void* l, const void* g) {
  __builtin_amdgcn_global_load_lds(
      (const __attribute__((address_space(1))) unsigned int*)g,
      (__attribute__((address_space(3))) unsigned int*)l, 16, 0, 0);
}

// ---------------- A1: e split+tile, B_k, zero counters ----------------------
__global__ __launch_bounds__(256) void k_eprep(const float* __restrict__ emb,
                                               float* __restrict__ ws,
                                               float* __restrict__ out) {
  const int k = blockIdx.x * 256 + threadIdx.x;   // 0..1023
  if (k == 0) { out[LOSS_OFF] = 0.0f; ((int*)ws)[WS_CNT] = 0; }
  const int ct = k >> 7, n = k & 127;
  const float* er = emb + k * DDIM;
  ushort* e1t = (ushort*)(ws + WS_E1);
  ushort* e2t = (ushort*)(ws + WS_E2);
  float bsum = 0.f;
  for (int s = 0; s < 8; ++s) {
#pragma unroll
    for (int kq = 0; kq < 4; ++kq) {
      const float4 v0 = *(const float4*)(er + s * 32 + kq * 8);
      const float4 v1 = *(const float4*)(er + s * 32 + kq * 8 + 4);
      const float v[8] = {v0.x, v0.y, v0.z, v0.w, v1.x, v1.y, v1.z, v1.w};
      u16x8 h, l;
#pragma unroll
      for (int j = 0; j < 8; ++j) {
        bsum = fmaf(v[j], v[j], bsum);
        h[j] = bf16_rne(v[j]);
        l[j] = bf16_rne(v[j] - bf16f(h[j]));
      }
      const int off = ((ct * 8 + s) * 4 + kq) * 1024 + n * 8;
      *(u16x8*)(e1t + off) = h;
      *(u16x8*)(e2t + off) = l;
    }
  }
  ws[WS_B + k] = bsum;
}

// ---------------- A2: A_n = ||z_n||^2 (bit-identical to rounds 3-5) ---------
__global__ __launch_bounds__(256) void k_znorm(const float* __restrict__ z,
                                               float* __restrict__ ws) {
  const int n = blockIdx.x * 256 + threadIdx.x;
  const int b = n >> 10, hw = n & 1023;
  const float* p = z + b * 262144 + hw;
  float a[8] = {0.f, 0.f, 0.f, 0.f, 0.f, 0.f, 0.f, 0.f};
  for (int d = 0; d < 256; d += 8) {
#pragma unroll
    for (int j = 0; j < 8; ++j) {
      const float v = p[(d + j) * 1024];
      a[j] = fmaf(v, v, a[j]);
    }
  }
  ws[WS_A + n] = ((a[0] + a[1]) + (a[2] + a[3])) + ((a[4] + a[5]) + (a[6] + a[7]));
}

// ---------------- A3: z transpose + split + tile ----------------------------
// Block = one rt (128 rows). Reads z[b][*][hw0..hw0+127], writes z1t/z2t
// tiles [rt][s][kq][m][8]. 4 passes of 64 c each via LDS.
__global__ __launch_bounds__(256) void k_zprep(const float* __restrict__ z,
                                               float* __restrict__ out) {
  __shared__ float lt[64][132];
  const int tid = threadIdx.x;
  const int rt = blockIdx.x;
  const int b = rt >> 3;
  const int hw0 = (rt & 7) << 7;
  ushort* z1t = (ushort*)out;
  ushort* z2t = (ushort*)out + Z2T_OFF;
  const int m = tid & 127, half = tid >> 7;   // write roles
  const int lc = tid >> 2, lq = tid & 3;      // load roles
  for (int p = 0; p < 4; ++p) {
    const int c0 = p << 6;
    const float* src = z + b * 262144 + (c0 + lc) * 1024 + hw0 + (lq << 5);
#pragma unroll
    for (int i = 0; i < 8; ++i)
      *(float4*)&lt[lc][(lq << 5) + (i << 2)] = *(const float4*)(src + (i << 2));
    __syncthreads();
    const int s = (p << 1) + half;
#pragma unroll
    for (int kq = 0; kq < 4; ++kq) {
      u16x8 h, l;
#pragma unroll
      for (int j = 0; j < 8; ++j) {
        const float v = lt[(half << 5) + (kq << 3) + j][m];
        h[j] = bf16_rne(v);
        l[j] = bf16_rne(v - bf16f(h[j]));
      }
      const int off = rt * 32768 + ((s << 2) + kq) * 1024 + (m << 3);
      *(u16x8*)(z1t + off) = h;
      *(u16x8*)(z2t + off) = l;
    }
    __syncthreads();
  }
}

// ---------------- B: MFMA score GEMM (pre-tiled streaming) ------------------
// BM=128 x BN=128, BK=32, 256 threads (4 waves, 2x2 grid, 64x64 per wave).
// LDS 64 KB dbuf; staging = pure global_load_lds (wave w owns array w).
__global__ __launch_bounds__(256, 2) void k_score(const float* __restrict__ out,
                                                  float* __restrict__ ws) {
  __shared__ __align__(16) ushort lds[2][16384];
  const int tid = threadIdx.x;
  const int id = blockIdx.x;
  const int rt = ((id >> 6) << 3) | (id & 7);   // co-locate a rt's 8 cts per XCD
  const int ct = (id >> 3) & 7;
  const int row0 = rt << 7;
  const int k0e = ct << 7;

  const ushort* z1t = (const ushort*)out;
  const ushort* z2t = (const ushort*)out + Z2T_OFF;
  const ushort* e1t = (const ushort*)(ws + WS_E1);
  const ushort* e2t = (const ushort*)(ws + WS_E2);

  const int w = tid >> 6, L = tid & 63;
  const int l15 = L & 15, kq = L >> 4;
  const int wr = w >> 1, wc = w & 1;

  const ushort* gbase[4] = {z1t + rt * 32768, z2t + rt * 32768,
                            e1t + (ct << 3) * 4096, e2t + (ct << 3) * 4096};
  auto stage = [&](int s, int bf) {
    const ushort* g = gbase[w] + (s << 12) + (L << 3);
#pragma unroll
    for (int i = 0; i < 8; ++i)
      gld16(&lds[bf][(w << 12) + (i << 9)], g + (i << 9));
  };

  f32x4 acc[4][4];
#pragma unroll
  for (int i = 0; i < 4; ++i)
#pragma unroll
    for (int j = 0; j < 4; ++j) acc[i][j] = (f32x4){0.f, 0.f, 0.f, 0.f};

  stage(0, 0);
  asm volatile("s_waitcnt vmcnt(0)" ::: "memory");
  __syncthreads();

  for (int s = 0; s < 8; ++s) {
    const int cur = s & 1;
    if (s < 7) stage(s + 1, cur ^ 1);
    bf16x8 a1[4], a2[4], b1[4], b2[4];
#pragma unroll
    for (int mi = 0; mi < 4; ++mi) {
      const int off = (kq << 10) + (((wr << 6) + (mi << 4) + l15) << 3);
      a1[mi] = *(const bf16x8*)&lds[cur][off];
      a2[mi] = *(const bf16x8*)&lds[cur][4096 + off];
    }
#pragma unroll
    for (int nj = 0; nj < 4; ++nj) {
      const int off = (kq << 10) + (((wc << 6) + (nj << 4) + l15) << 3);
      b1[nj] = *(const bf16x8*)&lds[cur][8192 + off];
      b2[nj] = *(const bf16x8*)&lds[cur][12288 + off];
    }
#pragma unroll
    for (int mi = 0; mi < 4; ++mi)
#pragma unroll
      for (int nj = 0; nj < 4; ++nj) {
        acc[mi][nj] = __builtin_amdgcn_mfma_f32_16x16x32_bf16(a2[mi], b1[nj], acc[mi][nj], 0, 0, 0);
        acc[mi][nj] = __builtin_amdgcn_mfma_f32_16x16x32_bf16(a1[mi], b2[nj], acc[mi][nj], 0, 0, 0);
        acc[mi][nj] = __builtin_amdgcn_mfma_f32_16x16x32_bf16(a1[mi], b1[nj], acc[mi][nj], 0, 0, 0);
      }
    asm volatile("s_waitcnt vmcnt(0)" ::: "memory");
    __syncthreads();
  }

  // epilogue: quantized score + per-chunk (v1, i1, v2)
  const int tc = (ct << 1) + wc;
#pragma unroll
  for (int mi = 0; mi < 4; ++mi) {
#pragma unroll
    for (int r = 0; r < 4; ++r) {
      const int ng = row0 + (wr << 6) + (mi << 4) + (kq << 2) + r;
      const float A = ws[WS_A + ng];
      float v1 = 3.0e38f, v2 = 3.0e38f;
      int i1 = 0;
#pragma unroll
      for (int nj = 0; nj < 4; ++nj) {
        const int kg = k0e + (wc << 6) + (nj << 4) + l15;
        const float B = ws[WS_B + kg];
        const float sc = fmaf(-2.0f, acc[mi][nj][r], A + B);
        if (sc < v1) { v2 = v1; v1 = sc; i1 = kg; }
        else if (sc < v2) v2 = sc;
      }
#pragma unroll
      for (int o = 1; o < 16; o <<= 1) {
        const float ov1 = __shfl_xor(v1, o);
        const float ov2 = __shfl_xor(v2, o);
        const int oi1 = __shfl_xor(i1, o);
        v2 = fminf(fminf(v2, ov2), fmaxf(v1, ov1));
        if (ov1 < v1 || (ov1 == v1 && oi1 < i1)) { v1 = ov1; i1 = oi1; }
      }
      if (l15 == 0) {
        const int base = (tc << 15) + ng;
        ws[WS_PV1 + base] = v1;
        ws[WS_PI1 + base] = (float)i1;
        ws[WS_PV2 + base] = v2;
      }
    }
  }
}

// ---------------- B2: merge 16 chunks; margin gate -> refine list -----------
__global__ __launch_bounds__(256) void k_reduce(float* __restrict__ ws,
                                                float* __restrict__ out) {
  const int row = blockIdx.x * 256 + threadIdx.x;
  float v1 = 3.0e38f, v2 = 3.0e38f, i1 = 0.f;
#pragma unroll
  for (int tc = 0; tc < 16; ++tc) {
    const int base = (tc << 15) + row;
    const float a1 = ws[WS_PV1 + base];
    const float ai = ws[WS_PI1 + base];
    const float a2 = ws[WS_PV2 + base];
    if (a1 < v1) { v2 = fminf(v1, a2); v1 = a1; i1 = ai; }
    else v2 = fminf(v2, a1);
  }
  out[IDX_OFF + row] = i1;
  if (v2 - v1 < REFINE_THR) {
    const int slot = atomicAdd((int*)ws + WS_CNT, 1);
    ((int*)ws)[WS_LIST + slot] = row;
  }
}

// ---------------- B3: exact re-solve, candidate chunks only -----------------
// One wave per gated row (grid-stride). Scans only chunks with
// chunk_v1 <= v1 + THR; each scanned code uses the bit-exact round-3 chain.
__global__ __launch_bounds__(256) void k_refine(const float* __restrict__ z,
                                                const float* __restrict__ emb,
                                                const float* __restrict__ ws,
                                                float* __restrict__ out) {
  __shared__ float zs[4][256];
  const int tid = threadIdx.x;
  const int w = tid >> 6, L = tid & 63;
  const int wg = blockIdx.x * 4 + w;
  const int cnt = ((const int*)ws)[WS_CNT];
  for (int e = wg; e < cnt; e += 1024) {
    const int row = ((const int*)ws)[WS_LIST + e];
    const int b = row >> 10, hw = row & 1023;
#pragma unroll
    for (int q = 0; q < 4; ++q)
      zs[w][(q << 6) + L] = z[b * 262144 + (((q << 6) + L) << 10) + hw];
    asm volatile("s_waitcnt lgkmcnt(0)" ::: "memory");
    float v1c = (L < 16) ? ws[WS_PV1 + (L << 15) + row] : 3.0e38f;
    float v1 = v1c;
#pragma unroll
    for (int o = 1; o < 64; o <<= 1) v1 = fminf(v1, __shfl_xor(v1, o));
    const float A = ws[WS_A + row];
    float bv = 3.0e38f;
    int bk = 0;
    for (int tc = 0; tc < 16; ++tc) {
      const float bc = __shfl(v1c, tc);
      if (bc <= v1 + REFINE_THR) {
        const int k = ((tc >> 1) << 7) + ((tc & 1) << 6) + L;
        const float* er = emb + k * DDIM;
        float s = 0.f;
        for (int d = 0; d < DDIM; ++d) s = fmaf(zs[w][d], er[d], s);
        const float sc = fmaf(-2.0f, s, A + ws[WS_B + k]);
        if (sc < bv) { bv = sc; bk = k; }   // tc ascending => lowest k kept
      }
    }
#pragma unroll
    for (int o = 1; o < 64; o <<= 1) {
      const float ov = __shfl_xor(bv, o);
      const int ok = __shfl_xor(bk, o);
      if (ov < bv || (ov == bv && ok < bk)) { bv = ov; bk = ok; }
    }
    if (L == 0) out[IDX_OFF + row] = (float)bk;
  }
}

// ---------------- C: z_q gather + loss ----------------
__global__ __launch_bounds__(256) void k_gather(const float* __restrict__ z,
                                                const float* __restrict__ emb,
                                                float* __restrict__ out) {
  const int tid = threadIdx.x;
  const int e0 = (blockIdx.x * 256 + tid) * 16;
  const int b = e0 >> 18;
  const int c = (e0 >> 10) & 255;
  const int n0 = (b << 10) + (e0 & 1023);
  float acc = 0.f;
#pragma unroll
  for (int g = 0; g < 4; ++g) {
    const float4 zv = *(const float4*)(z + e0 + g * 4);
    const float zz[4] = {zv.x, zv.y, zv.z, zv.w};
    float q[4];
#pragma unroll
    for (int j = 0; j < 4; ++j) {
      const int id = (int)(out[IDX_OFF + n0 + g * 4 + j] + 0.5f);
      const float e = emb[id * DDIM + c];
      q[j] = e;
      const float d = e - zz[j];
      acc = fmaf(d, d, acc);
    }
    const float4 qv = {q[0], q[1], q[2], q[3]};
    *(float4*)(out + e0 + g * 4) = qv;
  }
#pragma unroll
  for (int off = 32; off; off >>= 1) acc += __shfl_down(acc, off);
  __shared__ float sm[4];
  if ((tid & 63) == 0) sm[tid >> 6] = acc;
  __syncthreads();
  if (tid == 0)
    atomicAdd(out + LOSS_OFF,
              (sm[0] + sm[1] + sm[2] + sm[3]) * (1.25f / 8388608.0f));
}

extern "C" void kernel_launch(void* const* d_in, const int* in_sizes, int n_in,
                              void* d_out, int out_size, void* d_ws, size_t ws_size,
                              hipStream_t stream) {
  const float* z = (const float*)d_in[0];
  const float* emb = (const float*)d_in[1];
  float* out = (float*)d_out;
  float* ws = (float*)d_ws;

  k_eprep<<<4, 256, 0, stream>>>(emb, ws, out);
  k_znorm<<<128, 256, 0, stream>>>(z, ws);
  k_zprep<<<256, 256, 0, stream>>>(z, out);
  k_score<<<2048, 256, 0, stream>>>(out, ws);
  k_reduce<<<128, 256, 0, stream>>>(ws, out);
  k_refine<<<256, 256, 0, stream>>>(z, emb, ws, out);
  k_gather<<<2048, 256, 0, stream>>>(z, emb, out);
}

// Round 7
// 186.936 us; speedup vs baseline: 1.6694x; 1.1360x over previous
//
#include <hip/hip_runtime.h>

// VQGAN VectorQuantizer forward — register-streaming MFMA edition.
// z: (32,256,32,32) f32, emb: (1024,256) f32.
// d_out (float): [0..8388607] z_q | [8388608] loss | [8388609..] indices.
//
// Numerics: scores replicate np-f32 quantized formula s = fl(fl(A+B) - 2*dot).
// Main pass: dot via 3 bf16 MFMA GEMMs (z1e1+z1e2+z2e1; 2-term RNE splits),
// fragment/accumulation order bit-identical to round 6 (which passed). Rows with
// top-2 margin < 1.5e-4 are re-solved by k_refine with the EXACT round-3
// serial-fmaf chain over candidate chunks only. Loss = 1.25 * mean of best
// scores (error ~1e-5 relative, far under threshold).
//
// z_q region of d_out (dead until k_gather) holds z1t,z2t bf16 tiles (32 MB).
// Other scratch in d_ws (~7.3 MB):
#define WS_B 0            // [1024]   B_k = ||emb_k||^2
#define WS_A 1024         // [32768]  A_n = ||z_n||^2
#define WS_PV1 33792      // [16][32768] per-chunk best score
#define WS_PI1 558080     // [16][32768] per-chunk best index
#define WS_PV2 1082368    // [16][32768] per-chunk 2nd-best
#define WS_E1 1606656     // 262144 ushorts (e1 tiles)
#define WS_E2 1737728     // 262144 ushorts (e2 tiles)
#define WS_LIST 1868800   // [32768] int refine rows
#define WS_CNT 1901568    // int refine count

#define DDIM 256
#define LOSS_OFF 8388608
#define IDX_OFF 8388609
#define Z2T_OFF 8388608   // ushort offset of z2t within out
#define REFINE_THR 1.5e-4f

typedef __attribute__((ext_vector_type(8))) short bf16x8;
typedef __attribute__((ext_vector_type(4))) float f32x4;
typedef __attribute__((ext_vector_type(8))) ushort u16x8;

__device__ __forceinline__ ushort bf16_rne(float x) {
  unsigned u = __float_as_uint(x);
  return (ushort)((u + 0x7FFFu + ((u >> 16) & 1u)) >> 16);
}
__device__ __forceinline__ float bf16f(ushort h) {
  return __uint_as_float(((unsigned)h) << 16);
}

// ---------------- A1: e split+tile, B_k, zero counters ----------------------
__global__ __launch_bounds__(256) void k_eprep(const float* __restrict__ emb,
                                               float* __restrict__ ws,
                                               float* __restrict__ out) {
  const int k = blockIdx.x * 256 + threadIdx.x;   // 0..1023
  if (k == 0) { out[LOSS_OFF] = 0.0f; ((int*)ws)[WS_CNT] = 0; }
  const int ct = k >> 7, n = k & 127;
  const float* er = emb + k * DDIM;
  ushort* e1t = (ushort*)(ws + WS_E1);
  ushort* e2t = (ushort*)(ws + WS_E2);
  float bsum = 0.f;
  for (int s = 0; s < 8; ++s) {
#pragma unroll
    for (int kq = 0; kq < 4; ++kq) {
      const float4 v0 = *(const float4*)(er + s * 32 + kq * 8);
      const float4 v1 = *(const float4*)(er + s * 32 + kq * 8 + 4);
      const float v[8] = {v0.x, v0.y, v0.z, v0.w, v1.x, v1.y, v1.z, v1.w};
      u16x8 h, l;
#pragma unroll
      for (int j = 0; j < 8; ++j) {
        bsum = fmaf(v[j], v[j], bsum);
        h[j] = bf16_rne(v[j]);
        l[j] = bf16_rne(v[j] - bf16f(h[j]));
      }
      const int off = ((ct * 8 + s) * 4 + kq) * 1024 + n * 8;
      *(u16x8*)(e1t + off) = h;
      *(u16x8*)(e2t + off) = l;
    }
  }
  ws[WS_B + k] = bsum;
}

// ---------------- A2: z transpose + split + tile + ||z_n||^2 ----------------
// Block = one rt (128 rows). Reads z[b][*][hw0..hw0+127], writes z1t/z2t tiles
// [rt][s][kq][m][8] and A_n (fused: thread (half,m) sums its 128 d-values).
__global__ __launch_bounds__(256) void k_zprep(const float* __restrict__ z,
                                               float* __restrict__ out,
                                               float* __restrict__ ws) {
  __shared__ float lt[64][132];
  __shared__ float sq[128];
  const int tid = threadIdx.x;
  const int rt = blockIdx.x;
  const int b = rt >> 3;
  const int hw0 = (rt & 7) << 7;
  ushort* z1t = (ushort*)out;
  ushort* z2t = (ushort*)out + Z2T_OFF;
  const int m = tid & 127, half = tid >> 7;   // write roles
  const int lc = tid >> 2, lq = tid & 3;      // load roles
  float as[4] = {0.f, 0.f, 0.f, 0.f};
  for (int p = 0; p < 4; ++p) {
    const float* src = z + b * 262144 + ((p << 6) + lc) * 1024 + hw0 + (lq << 5);
#pragma unroll
    for (int i = 0; i < 8; ++i)
      *(float4*)&lt[lc][(lq << 5) + (i << 2)] = *(const float4*)(src + (i << 2));
    __syncthreads();
    const int s = (p << 1) + half;
#pragma unroll
    for (int kq = 0; kq < 4; ++kq) {
      u16x8 h, l;
#pragma unroll
      for (int j = 0; j < 8; ++j) {
        const float v = lt[(half << 5) + (kq << 3) + j][m];
        as[j & 3] = fmaf(v, v, as[j & 3]);
        h[j] = bf16_rne(v);
        l[j] = bf16_rne(v - bf16f(h[j]));
      }
      const int off = rt * 32768 + ((s << 2) + kq) * 1024 + (m << 3);
      *(u16x8*)(z1t + off) = h;
      *(u16x8*)(z2t + off) = l;
    }
    __syncthreads();
  }
  const float asum = (as[0] + as[1]) + (as[2] + as[3]);
  if (half) sq[m] = asum;
  __syncthreads();
  if (!half) ws[WS_A + rt * 128 + m] = asum + sq[m];
}

// ---------------- B: register-streaming MFMA score GEMM ---------------------
// Block 128x128 (4 waves, 2x2 grid, 64x64/wave). NO LDS, NO barriers: both
// operands are pre-tiled in fragment order, loaded straight to VGPRs,
// double-buffered across the 8 K-steps. Grid 2048 = 128 rt x 8 ct, swizzled
// so the 8 ct-blocks of one rt share an XCD's L2.
__global__ __launch_bounds__(256, 2) void k_score(const float* __restrict__ out,
                                                  float* __restrict__ ws) {
  const int tid = threadIdx.x;
  const int id = blockIdx.x;
  const int rt = ((id >> 6) << 3) | (id & 7);
  const int ct = (id >> 3) & 7;
  const int row0 = rt << 7;
  const int k0e = ct << 7;

  const ushort* z1t = (const ushort*)out;
  const ushort* z2t = (const ushort*)out + Z2T_OFF;
  const ushort* e1t = (const ushort*)(ws + WS_E1);
  const ushort* e2t = (const ushort*)(ws + WS_E2);

  const int w = tid >> 6, L = tid & 63;
  const int l15 = L & 15, kq = L >> 4;
  const int wr = w >> 1, wc = w & 1;

  // fragment base offsets (ushort units) at s=0; step s adds 4096
  const int abase = rt * 32768 + kq * 1024 + (wr * 64 + l15) * 8;
  const int bbase = ct * 32768 + kq * 1024 + (wc * 64 + l15) * 8;

  bf16x8 a1[2][4], a2[2][4], b1[2][4], b2[2][4];
  f32x4 acc[4][4];
#pragma unroll
  for (int i = 0; i < 4; ++i)
#pragma unroll
    for (int j = 0; j < 4; ++j) acc[i][j] = (f32x4){0.f, 0.f, 0.f, 0.f};

#pragma unroll
  for (int mi = 0; mi < 4; ++mi) {
    a1[0][mi] = *(const bf16x8*)(z1t + abase + mi * 128);
    a2[0][mi] = *(const bf16x8*)(z2t + abase + mi * 128);
    b1[0][mi] = *(const bf16x8*)(e1t + bbase + mi * 128);
    b2[0][mi] = *(const bf16x8*)(e2t + bbase + mi * 128);
  }

#pragma unroll
  for (int s = 0; s < 8; ++s) {
    const int cur = s & 1, nxt = cur ^ 1;
    if (s < 7) {
      const int ao = abase + (s + 1) * 4096;
      const int bo = bbase + (s + 1) * 4096;
#pragma unroll
      for (int mi = 0; mi < 4; ++mi) {
        a1[nxt][mi] = *(const bf16x8*)(z1t + ao + mi * 128);
        a2[nxt][mi] = *(const bf16x8*)(z2t + ao + mi * 128);
        b1[nxt][mi] = *(const bf16x8*)(e1t + bo + mi * 128);
        b2[nxt][mi] = *(const bf16x8*)(e2t + bo + mi * 128);
      }
    }
#pragma unroll
    for (int mi = 0; mi < 4; ++mi)
#pragma unroll
      for (int nj = 0; nj < 4; ++nj) {
        acc[mi][nj] = __builtin_amdgcn_mfma_f32_16x16x32_bf16(a2[cur][mi], b1[cur][nj], acc[mi][nj], 0, 0, 0);
        acc[mi][nj] = __builtin_amdgcn_mfma_f32_16x16x32_bf16(a1[cur][mi], b2[cur][nj], acc[mi][nj], 0, 0, 0);
        acc[mi][nj] = __builtin_amdgcn_mfma_f32_16x16x32_bf16(a1[cur][mi], b1[cur][nj], acc[mi][nj], 0, 0, 0);
      }
  }

  // epilogue: quantized score + per-chunk (v1, i1, v2) — identical to round 6
  const int tc = (ct << 1) + wc;
#pragma unroll
  for (int mi = 0; mi < 4; ++mi) {
#pragma unroll
    for (int r = 0; r < 4; ++r) {
      const int ng = row0 + (wr << 6) + (mi << 4) + (kq << 2) + r;
      const float A = ws[WS_A + ng];
      float v1 = 3.0e38f, v2 = 3.0e38f;
      int i1 = 0;
#pragma unroll
      for (int nj = 0; nj < 4; ++nj) {
        const int kg = k0e + (wc << 6) + (nj << 4) + l15;
        const float B = ws[WS_B + kg];
        const float sc = fmaf(-2.0f, acc[mi][nj][r], A + B);
        if (sc < v1) { v2 = v1; v1 = sc; i1 = kg; }
        else if (sc < v2) v2 = sc;
      }
#pragma unroll
      for (int o = 1; o < 16; o <<= 1) {
        const float ov1 = __shfl_xor(v1, o);
        const float ov2 = __shfl_xor(v2, o);
        const int oi1 = __shfl_xor(i1, o);
        v2 = fminf(fminf(v2, ov2), fmaxf(v1, ov1));
        if (ov1 < v1 || (ov1 == v1 && oi1 < i1)) { v1 = ov1; i1 = oi1; }
      }
      if (l15 == 0) {
        const int base = (tc << 15) + ng;
        ws[WS_PV1 + base] = v1;
        ws[WS_PI1 + base] = (float)i1;
        ws[WS_PV2 + base] = v2;
      }
    }
  }
}

// ---------------- B2: merge 16 chunks; gate -> refine list; loss ------------
__global__ __launch_bounds__(256) void k_reduce(float* __restrict__ ws,
                                                float* __restrict__ out) {
  const int tid = threadIdx.x;
  const int row = blockIdx.x * 256 + tid;
  float v1 = 3.0e38f, v2 = 3.0e38f, i1 = 0.f;
#pragma unroll
  for (int tc = 0; tc < 16; ++tc) {
    const int base = (tc << 15) + row;
    const float a1 = ws[WS_PV1 + base];
    const float ai = ws[WS_PI1 + base];
    const float a2 = ws[WS_PV2 + base];
    if (a1 < v1) { v2 = fminf(v1, a2); v1 = a1; i1 = ai; }
    else v2 = fminf(v2, a1);
  }
  out[IDX_OFF + row] = i1;
  if (v2 - v1 < REFINE_THR) {
    const int slot = atomicAdd((int*)ws + WS_CNT, 1);
    ((int*)ws)[WS_LIST + slot] = row;
  }
  // loss partial: sum of best scores (= ||z - e_idx||^2 within ~8e-5/row)
  float s = v1;
#pragma unroll
  for (int o = 32; o; o >>= 1) s += __shfl_down(s, o);
  __shared__ float sm[4];
  if ((tid & 63) == 0) sm[tid >> 6] = s;
  __syncthreads();
  if (tid == 0)
    atomicAdd(out + LOSS_OFF,
              (sm[0] + sm[1] + sm[2] + sm[3]) * (1.25f / 8388608.0f));
}

// ---------------- B3: exact re-solve, candidate chunks only -----------------
__global__ __launch_bounds__(256) void k_refine(const float* __restrict__ z,
                                                const float* __restrict__ emb,
                                                const float* __restrict__ ws,
                                                float* __restrict__ out) {
  __shared__ float zs[4][256];
  const int tid = threadIdx.x;
  const int w = tid >> 6, L = tid & 63;
  const int wg = blockIdx.x * 4 + w;
  const int cnt = ((const int*)ws)[WS_CNT];
  for (int e = wg; e < cnt; e += 1024) {
    const int row = ((const int*)ws)[WS_LIST + e];
    const int b = row >> 10, hw = row & 1023;
#pragma unroll
    for (int q = 0; q < 4; ++q)
      zs[w][(q << 6) + L] = z[b * 262144 + (((q << 6) + L) << 10) + hw];
    asm volatile("s_waitcnt lgkmcnt(0)" ::: "memory");
    float v1c = (L < 16) ? ws[WS_PV1 + (L << 15) + row] : 3.0e38f;
    float v1 = v1c;
#pragma unroll
    for (int o = 1; o < 64; o <<= 1) v1 = fminf(v1, __shfl_xor(v1, o));
    const float A = ws[WS_A + row];
    float bv = 3.0e38f;
    int bk = 0;
    for (int tc = 0; tc < 16; ++tc) {
      const float bc = __shfl(v1c, tc);
      if (bc <= v1 + REFINE_THR) {
        const int k = ((tc >> 1) << 7) + ((tc & 1) << 6) + L;
        const float* er = emb + k * DDIM;
        float s = 0.f;
        for (int d = 0; d < DDIM; ++d) s = fmaf(zs[w][d], er[d], s);
        const float sc = fmaf(-2.0f, s, A + ws[WS_B + k]);
        if (sc < bv) { bv = sc; bk = k; }   // tc ascending => lowest k kept
      }
    }
#pragma unroll
    for (int o = 1; o < 64; o <<= 1) {
      const float ov = __shfl_xor(bv, o);
      const int ok = __shfl_xor(bk, o);
      if (ov < bv || (ov == bv && ok < bk)) { bv = ov; bk = ok; }
    }
    if (L == 0) out[IDX_OFF + row] = (float)bk;
  }
}

// ---------------- C: z_q gather (pure) ----------------
__global__ __launch_bounds__(256) void k_gather(const float* __restrict__ emb,
                                                float* __restrict__ out) {
  const int tid = threadIdx.x;
  const int e0 = (blockIdx.x * 256 + tid) * 16;
  const int b = e0 >> 18;
  const int c = (e0 >> 10) & 255;
  const int n0 = (b << 10) + (e0 & 1023);
#pragma unroll
  for (int g = 0; g < 4; ++g) {
    float q[4];
#pragma unroll
    for (int j = 0; j < 4; ++j) {
      const int id = (int)(out[IDX_OFF + n0 + g * 4 + j] + 0.5f);
      q[j] = emb[id * DDIM + c];
    }
    const float4 qv = {q[0], q[1], q[2], q[3]};
    *(float4*)(out + e0 + g * 4) = qv;
  }
}

extern "C" void kernel_launch(void* const* d_in, const int* in_sizes, int n_in,
                              void* d_out, int out_size, void* d_ws, size_t ws_size,
                              hipStream_t stream) {
  const float* z = (const float*)d_in[0];
  const float* emb = (const float*)d_in[1];
  float* out = (float*)d_out;
  float* ws = (float*)d_ws;

  k_eprep<<<4, 256, 0, stream>>>(emb, ws, out);
  k_zprep<<<256, 256, 0, stream>>>(z, out, ws);
  k_score<<<2048, 256, 0, stream>>>(out, ws);
  k_reduce<<<128, 256, 0, stream>>>(ws, out);
  k_refine<<<256, 256, 0, stream>>>(z, emb, ws, out);
  k_gather<<<2048, 256, 0, stream>>>(emb, out);
}